// Round 10
// baseline (428.965 us; speedup 1.0000x reference)
//
#include <hip/hip_runtime.h>

// GQA (B=2,S=2048,E=2048,H=32,G=8,D=64), softmax over HEAD axis.
// R10 = R9 with the attn inner loop restructured to cut LDS-pipe ops and
// barriers (the measured ~33% LDS + 128-barrier serial chain):
//  - 64-k barrier rounds (2 tiles/round): 32 barrier-pairs instead of 64.
//  - b128 slab writes (4 consecutive k per reg quad), slab [g][q*72+k]
//    (stride 72 -> worst 2-way bank alias = free).
//  - reduce phase uses all 512 threads (8q x 64k = 512 positions).
//  - K reg double-buffer dropped (frees 32 VGPR for 2-tile scores).
// Spill marker: WRITE_SIZE must stay ~16.38 MB.

typedef unsigned short u16;
typedef unsigned int u32;
typedef __attribute__((ext_vector_type(8))) __bf16 bf16x8;
typedef __attribute__((ext_vector_type(4))) float f32x4;
typedef __attribute__((ext_vector_type(4))) float float4_t;

#define GLD16(ldsp, gp)                                                  \
  __builtin_amdgcn_global_load_lds(                                      \
      (__attribute__((address_space(1))) void*)(void*)(gp),              \
      (__attribute__((address_space(3))) void*)(void*)(ldsp), 16, 0, 0)

#define MFMA16(a, b, c) __builtin_amdgcn_mfma_f32_16x16x32_bf16(a, b, c, 0, 0, 0)

static __device__ __forceinline__ u16 f2bf(float f) {
  union { float f; u32 u; } v; v.f = f;
  u32 u = v.u;
  u32 r = (u + 0x7fffu + ((u >> 16) & 1u)) >> 16;  // RNE
  return (u16)r;
}

static __device__ __forceinline__ bf16x8 ld8(const u16* p) {
  return *(const bf16x8*)p;
}

#if __has_builtin(__builtin_amdgcn_exp2f)
static __device__ __forceinline__ float fexp2(float x) {
  return __builtin_amdgcn_exp2f(x);
}
#else
static __device__ __forceinline__ float fexp2(float x) {
  float r;
  asm("v_exp_f32 %0, %1\n\ts_nop 0" : "=v"(r) : "v"(x));
  return r;
}
#endif

static __device__ __forceinline__ u32 cvtpk(float a, float b) {
  u32 r;
  asm("v_cvt_pk_bf16_f32 %0, %1, %2" : "=v"(r) : "v"(a), "v"(b));
  return r;
}

// barrier that does NOT drain vmcnt (global prefetch stays in flight)
static __device__ __forceinline__ void barrier_lgkm() {
  asm volatile("s_waitcnt lgkmcnt(0)" ::: "memory");
  __builtin_amdgcn_s_barrier();
  asm volatile("" ::: "memory");
}

// sum over the 4 stride-4 lanes within each 16-lane row (head levels)
static __device__ __forceinline__ float hsum4(float v) {
  v += __builtin_bit_cast(float, __builtin_amdgcn_update_dpp(
           0, __builtin_bit_cast(int, v), 0x124, 0xf, 0xf, true));  // row_ror:4
  v += __builtin_bit_cast(float, __builtin_amdgcn_update_dpp(
           0, __builtin_bit_cast(int, v), 0x128, 0xf, 0xf, true));  // row_ror:8
  return v;
}

// ---------------- fused fp32 -> bf16 for all 5 tensors ----------------
__global__ void cvt_all(const float* __restrict__ x, const float* __restrict__ wq,
                        const float* __restrict__ wk, const float* __restrict__ wv,
                        const float* __restrict__ wo, u16* __restrict__ xb,
                        u16* __restrict__ wqb, u16* __restrict__ wkb,
                        u16* __restrict__ wvb, u16* __restrict__ wob) {
  int i = blockIdx.x * blockDim.x + threadIdx.x;
  const int stride = gridDim.x * blockDim.x;
  for (; i < 2359296; i += stride) {
    const float* src;
    u16* dst;
    int j;
    if (i < 1048576)      { src = x;  dst = xb;  j = i; }
    else if (i < 1572864) { src = wq; dst = wqb; j = i - 1048576; }
    else if (i < 1703936) { src = wk; dst = wkb; j = i - 1572864; }
    else if (i < 1835008) { src = wv; dst = wvb; j = i - 1703936; }
    else                  { src = wo; dst = wob; j = i - 1835008; }
    const float4_t* p = (const float4_t*)src + (size_t)j * 2;
    float4_t a = p[0], b = p[1];
    u32 w0 = (u32)f2bf(a[0]) | ((u32)f2bf(a[1]) << 16);
    u32 w1 = (u32)f2bf(a[2]) | ((u32)f2bf(a[3]) << 16);
    u32 w2 = (u32)f2bf(b[0]) | ((u32)f2bf(b[1]) << 16);
    u32 w3 = (u32)f2bf(b[2]) | ((u32)f2bf(b[3]) << 16);
    *(uint4*)(dst + (size_t)j * 8) = make_uint4(w0, w1, w2, w3);
  }
}

// ---------------- GEMM: C[M,N] = (A[M,K] @ W[N,K]^T + bias) * scale --------
template <int MODE>
__global__ __launch_bounds__(256, 2)
void gemm_bt(const u16* __restrict__ A, const u16* __restrict__ Bw,
             const float* __restrict__ bias,
             u16* __restrict__ Cb, float* __restrict__ Cf, int N, float scale) {
  constexpr int K = 2048;
  constexpr int SHSZ = (MODE == 2) ? (128 * 136) : 8192;
  __shared__ u16 sh[SHSZ];
  u16* As = sh;
  u16* Bs = sh + 4096;
  const int tid = threadIdx.x;
  const int lane = tid & 63;
  const int w = tid >> 6;
  const int m0 = blockIdx.y * 128;
  const int n0 = blockIdx.x * 128;
  const int wr = (w >> 1) * 64, wc = (w & 1) * 64;
  const int r15 = lane & 15, kq = lane >> 4;

  f32x4 acc[4][4] = {};

  for (int k0 = 0; k0 < K; k0 += 32) {
#pragma unroll
    for (int i = 0; i < 2; ++i) {
      int c = i * 256 + tid;
      int r = c >> 2, ch = c & 3;
      int sc = (ch ^ (r & 3)) * 8;
      GLD16(&As[c * 8], &A[(size_t)(m0 + r) * K + k0 + sc]);
      GLD16(&Bs[c * 8], &Bw[(size_t)(n0 + r) * K + k0 + sc]);
    }
    __syncthreads();
    bf16x8 af[4], bfr[4];
#pragma unroll
    for (int mt = 0; mt < 4; ++mt) {
      int r = wr + mt * 16 + r15;
      af[mt] = ld8(&As[r * 32 + ((kq ^ (r15 & 3)) * 8)]);
    }
#pragma unroll
    for (int nt = 0; nt < 4; ++nt) {
      int r = wc + nt * 16 + r15;
      bfr[nt] = ld8(&Bs[r * 32 + ((kq ^ (r15 & 3)) * 8)]);
    }
#pragma unroll
    for (int mt = 0; mt < 4; ++mt)
#pragma unroll
      for (int nt = 0; nt < 4; ++nt)
        acc[mt][nt] = MFMA16(af[mt], bfr[nt], acc[mt][nt]);
    __syncthreads();
  }

  if constexpr (MODE == 2) {
#pragma unroll
    for (int mt = 0; mt < 4; ++mt)
#pragma unroll
      for (int nt = 0; nt < 4; ++nt) {
        int col = wc + nt * 16 + r15;
        float bv = bias[n0 + col];
#pragma unroll
        for (int r = 0; r < 4; ++r) {
          int row = wr + mt * 16 + kq * 4 + r;
          sh[col * 136 + row] = f2bf(acc[mt][nt][r] + bv);
        }
      }
    __syncthreads();
    const int m0l = m0 & 2047;
    const int bb = m0 >> 11;
#pragma unroll
    for (int i = 0; i < 8; ++i) {
      int c = i * 256 + tid;
      int cc = c >> 4, so = c & 15;
      int X = cc * 136 + (so >> 2) * 32 + (so & 3) * 4;
      u32 A0 = *(const u32*)&sh[X + 0];
      u32 A1 = *(const u32*)&sh[X + 2];
      u32 B0 = *(const u32*)&sh[X + 16];
      u32 B1 = *(const u32*)&sh[X + 18];
      u32 w0 = __builtin_amdgcn_perm(B0, A0, 0x05040100u);
      u32 w1 = __builtin_amdgcn_perm(B0, A0, 0x07060302u);
      u32 w2 = __builtin_amdgcn_perm(B1, A1, 0x05040100u);
      u32 w3 = __builtin_amdgcn_perm(B1, A1, 0x07060302u);
      *(uint4*)&Cb[(size_t)(bb * 512 + n0 + cc) * 2048 + m0l + so * 8] =
          make_uint4(w0, w1, w2, w3);
    }
  } else {
    const int rb = kq * 4;
#pragma unroll
    for (int mt = 0; mt < 4; ++mt) {
#pragma unroll
      for (int nt = 0; nt < 4; ++nt) {
        int col = n0 + wc + nt * 16 + r15;
        float bv = bias[col];
#pragma unroll
        for (int r = 0; r < 4; ++r) {
          int row = m0 + wr + mt * 16 + rb + r;
          float v = (acc[mt][nt][r] + bv) * scale;
          if constexpr (MODE == 0) Cb[(size_t)row * N + col] = f2bf(v);
          else                     Cf[(size_t)row * N + col] = v;
        }
      }
    }
  }
}

// ---------------- fused attention (R10) ----------------
// Block = 512 thr (8 waves, wave = group g), 8 q-rows. Grid 512 = 2 blk/CU.
// 64-k rounds: K loads (8 b128) -> QK (16 mfma) -> V loads (8 b128) ->
// exp (32 v_exp) -> hsum4 -> 8x ds_write_b128 slab | B1 | reduce (all 512
// thr, 1 (q,k) position each) -> rsb | B2 | cvt_pk P -> PV (16 mfma).
__global__ __launch_bounds__(512, 2)
void attn_fused(const u16* __restrict__ Q, const u16* __restrict__ Kg,
                const u16* __restrict__ Vt, u16* __restrict__ O) {
  __shared__ float slab[8 * 576];  // [g][q*72 + k], q 0..7, k 0..63
  __shared__ float rsb[8 * 72];    // [q*72 + k] 1/sum

  const int tid = threadIdx.x;
  const int lane = tid & 63, g = tid >> 6;
  const int l15 = lane & 15, kq = lane >> 4;
  const int qr = l15 & 3, hl = l15 >> 2;

  // XCD pinning: batch b -> 4 XCDs (blocks of same b land on same XCDs)
  const int xcd = blockIdx.x & 7;
  const int b = xcd >> 2;
  const int qbase = ((((blockIdx.x >> 3) << 2) + (xcd & 3)) << 3);

  const u16* Qb = Q + (size_t)b * 2048 * 2048;
  const u16* Kb = Kg + (size_t)b * 2048 * 512;
  const u16* Vb = Vt + (size_t)b * 512 * 2048;  // k-interleaved Vt2

  bf16x8 qf[2][2];
#pragma unroll
  for (int qq = 0; qq < 2; ++qq)
#pragma unroll
    for (int t = 0; t < 2; ++t)
      qf[qq][t] = ld8(&Qb[(size_t)(qbase + qq * 4 + qr) * 2048 +
                          (g + 8 * hl) * 64 + t * 32 + kq * 8]);

  f32x4 acc[2][4] = {};

  const u16* kbase = &Kb[(size_t)l15 * 512 + g * 64 + kq * 8];
  const u16* vbase = &Vb[(size_t)(g * 64 + l15) * 2048 + kq * 8];

  for (int k0 = 0; k0 < 2048; k0 += 64) {
    // ---- K loads for both 32-k tiles of this round ----
    bf16x8 kf[4][2];
#pragma unroll
    for (int ko = 0; ko < 4; ++ko) {
      kf[ko][0] = ld8(kbase + (size_t)(k0 + ko * 16) * 512);
      kf[ko][1] = ld8(kbase + (size_t)(k0 + ko * 16) * 512 + 32);
    }
    // ---- QK (swapped): sc[qq][ko] -> e[k = ko*16 + kq*4 + r][hq] ----
    f32x4 sc[2][4];
#pragma unroll
    for (int qq = 0; qq < 2; ++qq)
#pragma unroll
      for (int ko = 0; ko < 4; ++ko) {
        f32x4 s = {};
        s = MFMA16(kf[ko][0], qf[qq][0], s);
        s = MFMA16(kf[ko][1], qf[qq][1], s);
        sc[qq][ko] = s;
      }
    // ---- V loads (latency covered by exp + barriers + reduce) ----
    bf16x8 vb[2][4];
#pragma unroll
    for (int t = 0; t < 2; ++t)
#pragma unroll
      for (int nt = 0; nt < 4; ++nt)
        vb[t][nt] = ld8(vbase + (size_t)nt * 32768 + k0 + t * 32);
    // ---- exp (K pre-scaled by 0.125*log2e) ----
#pragma unroll
    for (int qq = 0; qq < 2; ++qq)
#pragma unroll
      for (int ko = 0; ko < 4; ++ko)
#pragma unroll
        for (int r = 0; r < 4; ++r)
          sc[qq][ko][r] = fexp2(sc[qq][ko][r]);
    // ---- intra-wave 4-head sums + b128 slab writes ----
#pragma unroll
    for (int qq = 0; qq < 2; ++qq)
#pragma unroll
      for (int ko = 0; ko < 4; ++ko) {
        f32x4 u;
#pragma unroll
        for (int r = 0; r < 4; ++r) u[r] = hsum4(sc[qq][ko][r]);
        if (hl == 0)
          *(f32x4*)&slab[g * 576 + (qq * 4 + qr) * 72 + ko * 16 + kq * 4] = u;
      }

    barrier_lgkm();  // B1

    // ---- cross-g reduce: all 512 threads, one (q,k) each ----
    {
      const int q = tid >> 6, k = tid & 63;
      float s = 0.f;
#pragma unroll
      for (int gg = 0; gg < 8; ++gg) s += slab[gg * 576 + q * 72 + k];
      rsb[q * 72 + k] = __builtin_amdgcn_rcpf(s);
    }

    barrier_lgkm();  // B2

    // ---- pack P (cvt_pk, pairs (k,k+16) match Vt2 interleave) + PV ----
#pragma unroll
    for (int qq = 0; qq < 2; ++qq) {
      const float* rq = &rsb[(qq * 4 + qr) * 72 + kq * 4];
      f32x4 r0 = *(const f32x4*)(rq + 0);
      f32x4 r1 = *(const f32x4*)(rq + 16);
      f32x4 r2 = *(const f32x4*)(rq + 32);
      f32x4 r3 = *(const f32x4*)(rq + 48);
      u32 paw[4];
#pragma unroll
      for (int r = 0; r < 4; ++r)
        paw[r] = cvtpk(sc[qq][0][r] * r0[r], sc[qq][1][r] * r1[r]);
      bf16x8 pa0 = __builtin_bit_cast(bf16x8, *(uint4*)paw);
#pragma unroll
      for (int r = 0; r < 4; ++r)
        paw[r] = cvtpk(sc[qq][2][r] * r2[r], sc[qq][3][r] * r3[r]);
      bf16x8 pa1 = __builtin_bit_cast(bf16x8, *(uint4*)paw);
#pragma unroll
      for (int nt = 0; nt < 4; ++nt) {
        acc[qq][nt] = MFMA16(pa0, vb[0][nt], acc[qq][nt]);
        acc[qq][nt] = MFMA16(pa1, vb[1][nt], acc[qq][nt]);
      }
    }
  }

  // ---- epilogue: row kq*4+r -> (h-level kq, q-row r) ----
#pragma unroll
  for (int qq = 0; qq < 2; ++qq)
#pragma unroll
    for (int nt = 0; nt < 4; ++nt)
#pragma unroll
      for (int r = 0; r < 4; ++r)
        O[(size_t)(b * 2048 + qbase + qq * 4 + r) * 2048 +
          (g + 8 * kq) * 64 + nt * 16 + l15] = f2bf(acc[qq][nt][r]);
}

// ---------------- launcher ----------------
extern "C" void kernel_launch(void* const* d_in, const int* in_sizes, int n_in,
                              void* d_out, int out_size, void* d_ws, size_t ws_size,
                              hipStream_t stream) {
  (void)in_sizes; (void)n_in; (void)out_size; (void)ws_size;
  const float* x    = (const float*)d_in[0];
  const float* wq_w = (const float*)d_in[1];
  const float* wq_b = (const float*)d_in[2];
  const float* wk_w = (const float*)d_in[3];
  const float* wk_b = (const float*)d_in[4];
  const float* wv_w = (const float*)d_in[5];
  const float* wv_b = (const float*)d_in[6];
  const float* wo_w = (const float*)d_in[7];
  const float* wo_b = (const float*)d_in[8];
  float* out = (float*)d_out;

  char* p = (char*)d_ws;
  u16* xb  = (u16*)p; p += (size_t)4096 * 2048 * 2;
  u16* wqb = (u16*)p; p += (size_t)2048 * 2048 * 2;
  u16* wkb = (u16*)p; p += (size_t)512 * 2048 * 2;
  u16* wvb = (u16*)p; p += (size_t)512 * 2048 * 2;
  u16* wob = (u16*)p; p += (size_t)2048 * 2048 * 2;
  u16* Qb  = (u16*)p; p += (size_t)4096 * 2048 * 2;
  u16* Kb  = (u16*)p; p += (size_t)4096 * 512 * 2;
  u16* Vtb = (u16*)p; p += (size_t)1024 * 2048 * 2;
  u16* Ob  = (u16*)p; p += (size_t)4096 * 2048 * 2;

  hipLaunchKernelGGL(cvt_all, dim3(2048), dim3(256), 0, stream,
                     x, wq_w, wk_w, wv_w, wo_w, xb, wqb, wkb, wvb, wob);

  const float kscale = 0.125f * 1.44269504f;  // fold 1/sqrt(D) * log2(e) into K
  hipLaunchKernelGGL((gemm_bt<0>), dim3(16, 32), dim3(256), 0, stream,
                     xb, wqb, wq_b, Qb, (float*)nullptr, 2048, 1.0f);
  hipLaunchKernelGGL((gemm_bt<0>), dim3(4, 32),  dim3(256), 0, stream,
                     xb, wkb, wk_b, Kb, (float*)nullptr, 512, kscale);
  hipLaunchKernelGGL((gemm_bt<2>), dim3(4, 32),  dim3(256), 0, stream,
                     xb, wvb, wv_b, Vtb, (float*)nullptr, 512, 1.0f);

  hipLaunchKernelGGL(attn_fused, dim3(512), dim3(512), 0, stream, Qb, Kb, Vtb, Ob);

  hipLaunchKernelGGL((gemm_bt<1>), dim3(16, 32), dim3(256), 0, stream,
                     Ob, wob, wo_b, (u16*)nullptr, out, 2048, 1.0f);
}